// Round 2
// baseline (5245.001 us; speedup 1.0000x reference)
//
#include <hip/hip_runtime.h>
#include <hip/hip_bf16.h>
#include <math.h>

// Problem constants
#define NTOK  65536      // B*T
#define CDIM  512
#define NHEAD 8
#define HSZ   64
#define NLAYER 6
#define DFF   2048
#define VOCAB 65

typedef unsigned short u16;
typedef __attribute__((ext_vector_type(8))) __bf16 bf16x8;
typedef __attribute__((ext_vector_type(4))) float f32x4;
typedef __attribute__((ext_vector_type(8))) unsigned short ushort8;

__device__ __forceinline__ float b2f(u16 u) {
    union { unsigned int i; float f; } x; x.i = ((unsigned int)u) << 16; return x.f;
}
__device__ __forceinline__ u16 f2b(float f) {
    union { float f; unsigned int i; } x; x.f = f;
    unsigned int r = x.i + 0x7fffu + ((x.i >> 16) & 1u);   // RNE
    return (u16)(r >> 16);
}

__device__ __forceinline__ void async16(const u16* g, u16* l) {
    __builtin_amdgcn_global_load_lds(
        (const __attribute__((address_space(1))) void*)g,
        (__attribute__((address_space(3))) void*)l, 16, 0, 0);
}

// ---------------------------------------------------------------------------
// GEMM: C[M x N] = A[M x K] @ Bt[N x K]^T   (A,Bt bf16; fp32 MFMA accum)
// EPI: 0 plain->bf16, 1 +bias+res->bf16, 2 relu(+bias)->bf16, 3 +bias->f32 masked col<Nout
// Grid: (N/128, M/128), block 256. m97 structure: 128x128 tile, BK=32.
// ---------------------------------------------------------------------------
template<int EPI>
__global__ __launch_bounds__(256)
void gemm_bt(const u16* __restrict__ A, const u16* __restrict__ Bt,
             void* __restrict__ Cout, const float* __restrict__ bias,
             const u16* __restrict__ res, int K, int N, int Nout)
{
    __shared__ u16 lA[128 * 32];
    __shared__ u16 lB[128 * 32];
    const int tid  = threadIdx.x;
    const int m0   = blockIdx.y * 128;
    const int n0   = blockIdx.x * 128;
    const int lane = tid & 63;
    const int wv   = tid >> 6;
    const int wr   = (wv >> 1) * 64;   // wave row offset in tile
    const int wc   = (wv & 1) * 64;    // wave col offset in tile
    const int r16  = lane & 15;
    const int quad = lane >> 4;

    f32x4 acc[4][4] = {};

    // staging: 512 chunks of 16B (8 bf16); chunk c -> tile row c>>2, k-seg (c&3)*8
    const int ra0 = tid >> 2,          sa = (tid & 3) * 8;
    const int ra1 = (tid + 256) >> 2;
    const u16* gA0 = A  + (size_t)(m0 + ra0) * K + sa;
    const u16* gA1 = A  + (size_t)(m0 + ra1) * K + sa;
    const u16* gB0 = Bt + (size_t)(n0 + ra0) * K + sa;
    const u16* gB1 = Bt + (size_t)(n0 + ra1) * K + sa;
    u16* lA0 = &lA[(size_t)tid * 8];
    u16* lA1 = &lA[(size_t)(tid + 256) * 8];
    u16* lB0 = &lB[(size_t)tid * 8];
    u16* lB1 = &lB[(size_t)(tid + 256) * 8];

    for (int k0 = 0; k0 < K; k0 += 32) {
        async16(gA0 + k0, lA0);
        async16(gA1 + k0, lA1);
        async16(gB0 + k0, lB0);
        async16(gB1 + k0, lB1);
        __syncthreads();   // drains vmcnt -> LDS valid

        bf16x8 af[4], bfr[4];
#pragma unroll
        for (int i = 0; i < 4; i++)
            af[i] = *(const bf16x8*)(const void*)&lA[(wr + i * 16 + r16) * 32 + quad * 8];
#pragma unroll
        for (int j = 0; j < 4; j++)
            bfr[j] = *(const bf16x8*)(const void*)&lB[(wc + j * 16 + r16) * 32 + quad * 8];
#pragma unroll
        for (int i = 0; i < 4; i++)
#pragma unroll
            for (int j = 0; j < 4; j++)
                acc[i][j] = __builtin_amdgcn_mfma_f32_16x16x32_bf16(af[i], bfr[j], acc[i][j], 0, 0, 0);
        __syncthreads();   // all reads done before next stage overwrites
    }

    // epilogue: C/D layout col=lane&15, row=quad*4+reg  [m89-verified]
#pragma unroll
    for (int j = 0; j < 4; j++) {
        const int col = n0 + wc + j * 16 + r16;
        float bv = 0.f;
        if (EPI == 1 || EPI == 2) bv = bias[col];
        if (EPI == 3) bv = (col < Nout) ? bias[col] : 0.f;
#pragma unroll
        for (int i = 0; i < 4; i++) {
            const int row0 = m0 + wr + i * 16 + quad * 4;
#pragma unroll
            for (int r = 0; r < 4; r++) {
                float v = acc[i][j][r] + bv;
                const size_t rr = (size_t)(row0 + r);
                if (EPI == 1) v += b2f(res[rr * N + col]);
                if (EPI == 2) v = fmaxf(v, 0.f);
                if (EPI == 3) {
                    if (col < Nout) ((float*)Cout)[rr * (size_t)Nout + col] = v;
                } else {
                    ((u16*)Cout)[rr * N + col] = f2b(v);
                }
            }
        }
    }
}

// ---------------------------------------------------------------------------
// Attention: one wave per (b,h). T=8, HS=64. qkv layout [token][q|k|v, h*64+d].
// qkv/out are chunk-local pointers; nunits = tokens in chunk (= seqs*8 heads).
// NOTE: reference scale = C^-0.5 = 512^-0.5 (not HS^-0.5).
// ---------------------------------------------------------------------------
__global__ __launch_bounds__(256)
void attn_k(const u16* __restrict__ qkv, u16* __restrict__ out)
{
    __shared__ float sq[4][8][64], sk[4][8][64], sv[4][8][64], sp[4][64];
    const int w = threadIdx.x >> 6, lane = threadIdx.x & 63;
    const int unit = blockIdx.x * 4 + w;        // local b*8 + h
    const int b = unit >> 3, h = unit & 7;
    const size_t base = (size_t)b * 8 * 1536 + h * 64;
#pragma unroll
    for (int t = 0; t < 8; t++) {
        sq[w][t][lane] = b2f(qkv[base + t * 1536 + lane]);
        sk[w][t][lane] = b2f(qkv[base + t * 1536 + 512 + lane]);
        sv[w][t][lane] = b2f(qkv[base + t * 1536 + 1024 + lane]);
    }
    __syncthreads();
    const int t = lane >> 3, s = lane & 7;
    float sc = -1e30f;
    if (s <= t) {
        float d = 0.f;
#pragma unroll
        for (int c = 0; c < 64; c++) d += sq[w][t][c] * sk[w][s][c];
        sc = d * 0.04419417382415922f;          // 512^-0.5
    }
    float mx = sc;
#pragma unroll
    for (int m = 1; m < 8; m <<= 1) mx = fmaxf(mx, __shfl_xor(mx, m, 8));
    float e = __expf(sc - mx);
    if (s > t) e = 0.f;
    float sum = e;
#pragma unroll
    for (int m = 1; m < 8; m <<= 1) sum += __shfl_xor(sum, m, 8);
    sp[w][lane] = e / sum;
    __syncthreads();
#pragma unroll
    for (int tt = 0; tt < 8; tt++) {
        float a = 0.f;
#pragma unroll
        for (int ss = 0; ss < 8; ss++) a += sp[w][tt * 8 + ss] * sv[w][ss][lane];
        out[((size_t)b * 8 + tt) * 512 + h * 64 + lane] = f2b(a);
    }
}

// ---------------------------------------------------------------------------
// LayerNorm: wave per token, 8 elems/lane, shuffle reduction. bf16 in/out.
// ---------------------------------------------------------------------------
__global__ __launch_bounds__(256)
void ln_k(const u16* __restrict__ y, const float* __restrict__ g,
          const float* __restrict__ be, u16* __restrict__ x)
{
    const int w = threadIdx.x >> 6, lane = threadIdx.x & 63;
    const size_t tok = (size_t)blockIdx.x * 4 + w;
    const u16* row = y + tok * 512 + lane * 8;
    ushort8 raw = *(const ushort8*)(const void*)row;
    float v[8];
#pragma unroll
    for (int i = 0; i < 8; i++) v[i] = b2f(raw[i]);
    float s = 0.f;
#pragma unroll
    for (int i = 0; i < 8; i++) s += v[i];
#pragma unroll
    for (int m = 1; m < 64; m <<= 1) s += __shfl_xor(s, m, 64);
    const float mu = s * (1.f / 512.f);
    float q = 0.f;
#pragma unroll
    for (int i = 0; i < 8; i++) { float d = v[i] - mu; q += d * d; }
#pragma unroll
    for (int m = 1; m < 64; m <<= 1) q += __shfl_xor(q, m, 64);
    const float inv = rsqrtf(q * (1.f / 512.f) + 1e-5f);
    f32x4 g0  = *(const f32x4*)(const void*)&g[lane * 8];
    f32x4 g1  = *(const f32x4*)(const void*)&g[lane * 8 + 4];
    f32x4 b0  = *(const f32x4*)(const void*)&be[lane * 8];
    f32x4 b1v = *(const f32x4*)(const void*)&be[lane * 8 + 4];
    ushort8 o;
#pragma unroll
    for (int i = 0; i < 4; i++) o[i]     = f2b((v[i] - mu) * inv * g0[i] + b0[i]);
#pragma unroll
    for (int i = 0; i < 4; i++) o[i + 4] = f2b((v[i + 4] - mu) * inv * g1[i] + b1v[i]);
    *(ushort8*)(void*)&x[tok * 512 + lane * 8] = o;
}

// ---------------------------------------------------------------------------
// Embedding: block per token, x = tok_table[idx] + pos_table -> bf16
// ---------------------------------------------------------------------------
__global__ __launch_bounds__(256)
void embed_k(const int* __restrict__ idx, const float* __restrict__ tokt,
             const float* __restrict__ pos, u16* __restrict__ xb)
{
    const int tk = blockIdx.x;
    const int t = tk & 7;
    const int ix = idx[tk];
    const int c = threadIdx.x;
    const size_t o = (size_t)tk * 512;
    xb[o + c]       = f2b(tokt[(size_t)ix * 512 + c]       + pos[t * 512 + c]);
    xb[o + c + 256] = f2b(tokt[(size_t)ix * 512 + c + 256] + pos[t * 512 + c + 256]);
}

// ---------------------------------------------------------------------------
// Weight converts (fp32 -> bf16 B^T layouts), once per launch
// ---------------------------------------------------------------------------
// Wqkv_t[l][j][c]: j in [0,1536): q(h*64+d) | k | v ; from wq/wk/wv (L,H,C,HS)
__global__ __launch_bounds__(256)
void conv_qkv_k(const float* __restrict__ wq, const float* __restrict__ wk,
                const float* __restrict__ wv, u16* __restrict__ out)
{
    int gid = blockIdx.x * 256 + threadIdx.x;        // < 6*1536*512
    int l = gid / 786432;
    int rem = gid - l * 786432;
    int j = rem >> 9, c = rem & 511;
    int sel = j >> 9;
    int jj = j & 511;
    int h = jj >> 6, d = jj & 63;
    const float* src = (sel == 0) ? wq : (sel == 1) ? wk : wv;
    out[gid] = f2b(src[(((size_t)l * 8 + h) * 512 + c) * 64 + d]);
}

// out[l][n][k] = in[l][k][n]  (per-layer K x N -> N x K transpose)
__global__ __launch_bounds__(256)
void conv_t_k(const float* __restrict__ in, u16* __restrict__ out, int K, int N)
{
    int gid = blockIdx.x * 256 + threadIdx.x;        // < 6*K*N
    int per = K * N;
    int l = gid / per;
    int rem = gid - l * per;
    int n = rem / K;
    int k = rem - n * K;
    out[gid] = f2b(in[(size_t)l * per + (size_t)k * N + n]);
}

// lm_t[128][512], rows >= 65 zero-padded
__global__ __launch_bounds__(256)
void conv_lm_k(const float* __restrict__ lm_w, u16* __restrict__ out)
{
    int gid = blockIdx.x * 256 + threadIdx.x;        // < 128*512
    int n = gid >> 9, c = gid & 511;
    out[gid] = (n < VOCAB) ? f2b(lm_w[(size_t)c * VOCAB + n]) : (u16)0;
}

// ---------------------------------------------------------------------------
extern "C" void kernel_launch(void* const* d_in, const int* in_sizes, int n_in,
                              void* d_out, int out_size, void* d_ws, size_t ws_size,
                              hipStream_t stream)
{
    const int*   idx    = (const int*)  d_in[0];
    const float* tokt   = (const float*)d_in[1];
    const float* post   = (const float*)d_in[2];
    const float* wq     = (const float*)d_in[3];
    const float* wk     = (const float*)d_in[4];
    const float* wvp    = (const float*)d_in[5];
    const float* proj_w = (const float*)d_in[6];
    const float* proj_b = (const float*)d_in[7];
    const float* w1     = (const float*)d_in[8];
    const float* b1     = (const float*)d_in[9];
    const float* w2     = (const float*)d_in[10];
    const float* b2     = (const float*)d_in[11];
    const float* ln1_g  = (const float*)d_in[12];
    const float* ln1_b  = (const float*)d_in[13];
    const float* ln2_g  = (const float*)d_in[14];
    const float* ln2_b  = (const float*)d_in[15];
    const float* lm_w   = (const float*)d_in[16];
    const float* lm_b   = (const float*)d_in[17];
    float* out = (float*)d_out;

    char* ws = (char*)d_ws;
    // Fixed workspace layout (bytes, all 256-aligned):
    u16* wqkvt = (u16*)(ws + 0);                     //  9,437,184  (6 x 1536 x 512)
    u16* wprjt = (u16*)(ws + 9437184);               //  3,145,728  (6 x 512 x 512)
    u16* ww1t  = (u16*)(ws + 12582912);              // 12,582,912  (6 x 2048 x 512)
    u16* ww2t  = (u16*)(ws + 25165824);              // 12,582,912  (6 x 512 x 2048)
    u16* wlmt  = (u16*)(ws + 37748736);              //    131,072  (128 x 512)
    u16* xb    = (u16*)(ws + 37879808);              // 67,108,864  residual (bf16)
    u16* yb    = (u16*)(ws + 104988672);             // 67,108,864  pre-LN sum
    char* big  = ws + 172097536;                     // chunk*4096 bytes transient

    // Adaptive token chunking so total fits ws_size. Transient need per chunk:
    //   qkv (chunk*1536*2) + attno (chunk*512*2) = chunk*4096  (attn phase)
    //   h1  (chunk*2048*2)                       = chunk*4096  (mlp phase)
    const size_t fixed_bytes = 172097536ull;
    int chunk = 4096;
    const int cands[4] = {65536, 32768, 16384, 8192};
    for (int i = 0; i < 4; i++) {
        if (fixed_bytes + (size_t)cands[i] * 4096ull <= ws_size) { chunk = cands[i]; break; }
    }
    const int nchunks = NTOK / chunk;
    u16* qkvc  = (u16*)big;                          // chunk x 1536
    u16* attnc = (u16*)(big + (size_t)chunk * 3072); // chunk x 512
    u16* h1c   = (u16*)big;                          // chunk x 2048

    // weight conversion (every call: d_ws is re-poisoned before timed launches)
    conv_qkv_k<<<6 * 1536 * 512 / 256, 256, 0, stream>>>(wq, wk, wvp, wqkvt);
    conv_t_k  <<<6 * 512 * 512 / 256, 256, 0, stream>>>(proj_w, wprjt, 512, 512);
    conv_t_k  <<<6 * 512 * 2048 / 256, 256, 0, stream>>>(w1, ww1t, 512, 2048);
    conv_t_k  <<<6 * 2048 * 512 / 256, 256, 0, stream>>>(w2, ww2t, 2048, 512);
    conv_lm_k <<<128 * 512 / 256, 256, 0, stream>>>(lm_w, wlmt);

    embed_k<<<NTOK, 256, 0, stream>>>(idx, tokt, post, xb);

    for (int l = 0; l < NLAYER; l++) {
        // ---- attention phase, chunked over tokens ----
        for (int c = 0; c < nchunks; c++) {
            const size_t t0 = (size_t)c * chunk;
            // qkv = x @ Wqkv  (no bias)
            gemm_bt<0><<<dim3(12, chunk / 128), 256, 0, stream>>>(
                xb + t0 * 512, wqkvt + (size_t)l * 786432, qkvc,
                nullptr, nullptr, 512, 1536, 1536);
            // attention (chunk-local)
            attn_k<<<chunk / 4, 256, 0, stream>>>(qkvc, attnc);
            // y = attno @ proj_w + proj_b + x
            gemm_bt<1><<<dim3(4, chunk / 128), 256, 0, stream>>>(
                attnc, wprjt + (size_t)l * 262144, yb + t0 * 512,
                proj_b + l * 512, xb + t0 * 512, 512, 512, 512);
        }
        // x = LN1(y)
        ln_k<<<NTOK / 4, 256, 0, stream>>>(yb, ln1_g + l * 512, ln1_b + l * 512, xb);
        // ---- MLP phase, chunked over tokens ----
        for (int c = 0; c < nchunks; c++) {
            const size_t t0 = (size_t)c * chunk;
            // h1 = relu(x @ w1 + b1)
            gemm_bt<2><<<dim3(16, chunk / 128), 256, 0, stream>>>(
                xb + t0 * 512, ww1t + (size_t)l * 1048576, h1c,
                b1 + l * 2048, nullptr, 512, 2048, 2048);
            // y = h1 @ w2 + b2 + x
            gemm_bt<1><<<dim3(4, chunk / 128), 256, 0, stream>>>(
                h1c, ww2t + (size_t)l * 1048576, yb + t0 * 512,
                b2 + l * 512, xb + t0 * 512, 2048, 512, 512);
        }
        // x = LN2(y)
        ln_k<<<NTOK / 4, 256, 0, stream>>>(yb, ln2_g + l * 512, ln2_b + l * 512, xb);
    }

    // logits = x @ lm_w + lm_b  (N padded to 128, masked fp32 store, Nout=65)
    gemm_bt<3><<<dim3(1, 512), 256, 0, stream>>>(
        xb, wlmt, out, lm_b, nullptr, 512, 128, VOCAB);
}

// Round 3
// 4321.337 us; speedup vs baseline: 1.2137x; 1.2137x over previous
//
#include <hip/hip_runtime.h>
#include <hip/hip_bf16.h>
#include <math.h>

// Problem constants
#define NTOK  65536      // B*T
#define CDIM  512
#define NHEAD 8
#define HSZ   64
#define NLAYER 6
#define DFF   2048
#define VOCAB 65

typedef unsigned short u16;
typedef __attribute__((ext_vector_type(8))) __bf16 bf16x8;
typedef __attribute__((ext_vector_type(4))) float f32x4;
typedef __attribute__((ext_vector_type(8))) unsigned short ushort8;

__device__ __forceinline__ float b2f(u16 u) {
    union { unsigned int i; float f; } x; x.i = ((unsigned int)u) << 16; return x.f;
}
__device__ __forceinline__ u16 f2b(float f) {
    union { float f; unsigned int i; } x; x.f = f;
    unsigned int r = x.i + 0x7fffu + ((x.i >> 16) & 1u);   // RNE
    return (u16)(r >> 16);
}

__device__ __forceinline__ void async16(const u16* g, u16* l) {
    __builtin_amdgcn_global_load_lds(
        (const __attribute__((address_space(1))) void*)g,
        (__attribute__((address_space(3))) void*)l, 16, 0, 0);
}

// ---------------------------------------------------------------------------
// GEMM: C[M x N] = A[M x K] @ Bt[N x K]^T   (A,Bt bf16; fp32 MFMA accum)
// EPI: 0 plain->bf16, 1 +bias+res->bf16 (res may alias Cout: in-place),
//      2 relu(+bias)->bf16, 3 +bias->f32 masked col<Nout
// 128x128 tile, BK=64 (two BK=32 sub-tiles per barrier pair), LDS 32 KB.
// XCD swizzle: id%8 = XCD; each XCD owns complete m-stripes so all n-tiles
// of an m-stripe share that XCD's L2 (kills the 8x A over-fetch seen in R2).
// Requires gridDim.y % 8 == 0.
// ---------------------------------------------------------------------------
template<int EPI>
__global__ __launch_bounds__(256, 4)
void gemm_bt(const u16* __restrict__ A, const u16* __restrict__ Bt,
             void* __restrict__ Cout, const float* __restrict__ bias,
             const u16* __restrict__ res, int K, int N, int Nout)
{
    __shared__ u16 lA[2 * 128 * 32];   // [s][row][32]
    __shared__ u16 lB[2 * 128 * 32];
    const int tid  = threadIdx.x;

    // XCD-aware swizzle
    const int Nx = gridDim.x;
    const int id = blockIdx.y * Nx + blockIdx.x;
    const int xcd = id & 7;
    const int j   = id >> 3;
    const int mt  = xcd + 8 * (j / Nx);
    const int nt  = j - (j / Nx) * Nx;
    const int m0  = mt * 128;
    const int n0  = nt * 128;

    const int lane = tid & 63;
    const int wv   = tid >> 6;
    const int wr   = (wv >> 1) * 64;   // wave row offset in tile
    const int wc   = (wv & 1) * 64;    // wave col offset in tile
    const int r16  = lane & 15;
    const int quad = lane >> 4;

    f32x4 acc[4][4] = {};

    // staging: 4 chunks of 16B per thread per matrix per BK=64 step.
    // chunk c = i*256+tid -> s = c>>9 (k-half), row = (c>>2)&127, kseg=(c&3)*8
    const int srow = tid >> 2, skseg = (tid & 3) * 8;
    const u16* pA = A  + (size_t)(m0 + srow) * K + skseg;
    const u16* pB = Bt + (size_t)(n0 + srow) * K + skseg;
    const size_t r64K = (size_t)64 * K;
    u16* lA0 = &lA[(size_t)tid * 8];
    u16* lB0 = &lB[(size_t)tid * 8];

    for (int k0 = 0; k0 < K; k0 += 64) {
        async16(pA + k0,             lA0);
        async16(pA + r64K + k0,      lA0 + 2048);
        async16(pA + 32 + k0,        lA0 + 4096);
        async16(pA + r64K + 32 + k0, lA0 + 6144);
        async16(pB + k0,             lB0);
        async16(pB + r64K + k0,      lB0 + 2048);
        async16(pB + 32 + k0,        lB0 + 4096);
        async16(pB + r64K + 32 + k0, lB0 + 6144);
        __syncthreads();   // drains vmcnt -> LDS valid

#pragma unroll
        for (int s = 0; s < 2; s++) {
            const int sb = s * 4096;
            bf16x8 af[4], bfr[4];
#pragma unroll
            for (int i = 0; i < 4; i++)
                af[i] = *(const bf16x8*)(const void*)&lA[sb + (wr + i * 16 + r16) * 32 + quad * 8];
#pragma unroll
            for (int jj = 0; jj < 4; jj++)
                bfr[jj] = *(const bf16x8*)(const void*)&lB[sb + (wc + jj * 16 + r16) * 32 + quad * 8];
#pragma unroll
            for (int i = 0; i < 4; i++)
#pragma unroll
                for (int jj = 0; jj < 4; jj++)
                    acc[i][jj] = __builtin_amdgcn_mfma_f32_16x16x32_bf16(af[i], bfr[jj], acc[i][jj], 0, 0, 0);
        }
        __syncthreads();   // all reads done before next stage overwrites
    }

    // epilogue: C/D layout col=lane&15, row=quad*4+reg  [m89-verified]
#pragma unroll
    for (int jj = 0; jj < 4; jj++) {
        const int col = n0 + wc + jj * 16 + r16;
        float bv = 0.f;
        if (EPI == 1 || EPI == 2) bv = bias[col];
        if (EPI == 3) bv = (col < Nout) ? bias[col] : 0.f;
#pragma unroll
        for (int i = 0; i < 4; i++) {
            const int row0 = m0 + wr + i * 16 + quad * 4;
#pragma unroll
            for (int r = 0; r < 4; r++) {
                float v = acc[i][jj][r] + bv;
                const size_t rr = (size_t)(row0 + r);
                if (EPI == 1) v += b2f(res[rr * N + col]);
                if (EPI == 2) v = fmaxf(v, 0.f);
                if (EPI == 3) {
                    if (col < Nout) ((float*)Cout)[rr * (size_t)Nout + col] = v;
                } else {
                    ((u16*)Cout)[rr * N + col] = f2b(v);
                }
            }
        }
    }
}

// ---------------------------------------------------------------------------
// Attention: one wave per (b,h). T=8, HS=64. qkv layout [token][q|k|v, h*64+d].
// NOTE: reference scale = C^-0.5 = 512^-0.5 (not HS^-0.5).
// ---------------------------------------------------------------------------
__global__ __launch_bounds__(256)
void attn_k(const u16* __restrict__ qkv, u16* __restrict__ out)
{
    __shared__ float sq[4][8][64], sk[4][8][64], sv[4][8][64], sp[4][64];
    const int w = threadIdx.x >> 6, lane = threadIdx.x & 63;
    const int unit = blockIdx.x * 4 + w;        // local b*8 + h
    const int b = unit >> 3, h = unit & 7;
    const size_t base = (size_t)b * 8 * 1536 + h * 64;
#pragma unroll
    for (int t = 0; t < 8; t++) {
        sq[w][t][lane] = b2f(qkv[base + t * 1536 + lane]);
        sk[w][t][lane] = b2f(qkv[base + t * 1536 + 512 + lane]);
        sv[w][t][lane] = b2f(qkv[base + t * 1536 + 1024 + lane]);
    }
    __syncthreads();
    const int t = lane >> 3, s = lane & 7;
    float sc = -1e30f;
    if (s <= t) {
        float d = 0.f;
#pragma unroll
        for (int c = 0; c < 64; c++) d += sq[w][t][c] * sk[w][s][c];
        sc = d * 0.04419417382415922f;          // 512^-0.5
    }
    float mx = sc;
#pragma unroll
    for (int m = 1; m < 8; m <<= 1) mx = fmaxf(mx, __shfl_xor(mx, m, 8));
    float e = __expf(sc - mx);
    if (s > t) e = 0.f;
    float sum = e;
#pragma unroll
    for (int m = 1; m < 8; m <<= 1) sum += __shfl_xor(sum, m, 8);
    sp[w][lane] = e / sum;
    __syncthreads();
#pragma unroll
    for (int tt = 0; tt < 8; tt++) {
        float a = 0.f;
#pragma unroll
        for (int ss = 0; ss < 8; ss++) a += sp[w][tt * 8 + ss] * sv[w][ss][lane];
        out[((size_t)b * 8 + tt) * 512 + h * 64 + lane] = f2b(a);
    }
}

// ---------------------------------------------------------------------------
// LayerNorm: wave per token, 8 elems/lane, shuffle reduction. In-place OK.
// ---------------------------------------------------------------------------
__global__ __launch_bounds__(256)
void ln_k(const u16* __restrict__ y, const float* __restrict__ g,
          const float* __restrict__ be, u16* __restrict__ x)
{
    const int w = threadIdx.x >> 6, lane = threadIdx.x & 63;
    const size_t tok = (size_t)blockIdx.x * 4 + w;
    const u16* row = y + tok * 512 + lane * 8;
    ushort8 raw = *(const ushort8*)(const void*)row;
    float v[8];
#pragma unroll
    for (int i = 0; i < 8; i++) v[i] = b2f(raw[i]);
    float s = 0.f;
#pragma unroll
    for (int i = 0; i < 8; i++) s += v[i];
#pragma unroll
    for (int m = 1; m < 64; m <<= 1) s += __shfl_xor(s, m, 64);
    const float mu = s * (1.f / 512.f);
    float q = 0.f;
#pragma unroll
    for (int i = 0; i < 8; i++) { float d = v[i] - mu; q += d * d; }
#pragma unroll
    for (int m = 1; m < 64; m <<= 1) q += __shfl_xor(q, m, 64);
    const float inv = rsqrtf(q * (1.f / 512.f) + 1e-5f);
    f32x4 g0  = *(const f32x4*)(const void*)&g[lane * 8];
    f32x4 g1  = *(const f32x4*)(const void*)&g[lane * 8 + 4];
    f32x4 b0  = *(const f32x4*)(const void*)&be[lane * 8];
    f32x4 b1v = *(const f32x4*)(const void*)&be[lane * 8 + 4];
    ushort8 o;
#pragma unroll
    for (int i = 0; i < 4; i++) o[i]     = f2b((v[i] - mu) * inv * g0[i] + b0[i]);
#pragma unroll
    for (int i = 0; i < 4; i++) o[i + 4] = f2b((v[i + 4] - mu) * inv * g1[i] + b1v[i]);
    *(ushort8*)(void*)&x[tok * 512 + lane * 8] = o;
}

// ---------------------------------------------------------------------------
// Embedding: block per token, x = tok_table[idx] + pos_table -> bf16
// ---------------------------------------------------------------------------
__global__ __launch_bounds__(256)
void embed_k(const int* __restrict__ idx, const float* __restrict__ tokt,
             const float* __restrict__ pos, u16* __restrict__ xb)
{
    const int tk = blockIdx.x;
    const int t = tk & 7;
    const int ix = idx[tk];
    const int c = threadIdx.x;
    const size_t o = (size_t)tk * 512;
    xb[o + c]       = f2b(tokt[(size_t)ix * 512 + c]       + pos[t * 512 + c]);
    xb[o + c + 256] = f2b(tokt[(size_t)ix * 512 + c + 256] + pos[t * 512 + c + 256]);
}

// ---------------------------------------------------------------------------
// Weight converts (fp32 -> bf16 B^T layouts), once per launch
// ---------------------------------------------------------------------------
__global__ __launch_bounds__(256)
void conv_qkv_k(const float* __restrict__ wq, const float* __restrict__ wk,
                const float* __restrict__ wv, u16* __restrict__ out)
{
    int gid = blockIdx.x * 256 + threadIdx.x;        // < 6*1536*512
    int l = gid / 786432;
    int rem = gid - l * 786432;
    int j = rem >> 9, c = rem & 511;
    int sel = j >> 9;
    int jj = j & 511;
    int h = jj >> 6, d = jj & 63;
    const float* src = (sel == 0) ? wq : (sel == 1) ? wk : wv;
    out[gid] = f2b(src[(((size_t)l * 8 + h) * 512 + c) * 64 + d]);
}

// out[l][n][k] = in[l][k][n]  (per-layer K x N -> N x K transpose)
__global__ __launch_bounds__(256)
void conv_t_k(const float* __restrict__ in, u16* __restrict__ out, int K, int N)
{
    int gid = blockIdx.x * 256 + threadIdx.x;        // < 6*K*N
    int per = K * N;
    int l = gid / per;
    int rem = gid - l * per;
    int n = rem / K;
    int k = rem - n * K;
    out[gid] = f2b(in[(size_t)l * per + (size_t)k * N + n]);
}

// lm_t[128][512], rows >= 65 zero-padded
__global__ __launch_bounds__(256)
void conv_lm_k(const float* __restrict__ lm_w, u16* __restrict__ out)
{
    int gid = blockIdx.x * 256 + threadIdx.x;        // < 128*512
    int n = gid >> 9, c = gid & 511;
    out[gid] = (n < VOCAB) ? f2b(lm_w[(size_t)c * VOCAB + n]) : (u16)0;
}

// ---------------------------------------------------------------------------
extern "C" void kernel_launch(void* const* d_in, const int* in_sizes, int n_in,
                              void* d_out, int out_size, void* d_ws, size_t ws_size,
                              hipStream_t stream)
{
    const int*   idx    = (const int*)  d_in[0];
    const float* tokt   = (const float*)d_in[1];
    const float* post   = (const float*)d_in[2];
    const float* wq     = (const float*)d_in[3];
    const float* wk     = (const float*)d_in[4];
    const float* wvp    = (const float*)d_in[5];
    const float* proj_w = (const float*)d_in[6];
    const float* proj_b = (const float*)d_in[7];
    const float* w1     = (const float*)d_in[8];
    const float* b1     = (const float*)d_in[9];
    const float* w2     = (const float*)d_in[10];
    const float* b2     = (const float*)d_in[11];
    const float* ln1_g  = (const float*)d_in[12];
    const float* ln1_b  = (const float*)d_in[13];
    const float* ln2_g  = (const float*)d_in[14];
    const float* ln2_b  = (const float*)d_in[15];
    const float* lm_w   = (const float*)d_in[16];
    const float* lm_b   = (const float*)d_in[17];
    float* out = (float*)d_out;

    char* ws = (char*)d_ws;
    // Fixed workspace layout (bytes, all 256-aligned):
    u16* wqkvt = (u16*)(ws + 0);                     //  9,437,184  (6 x 1536 x 512)
    u16* wprjt = (u16*)(ws + 9437184);               //  3,145,728  (6 x 512 x 512)
    u16* ww1t  = (u16*)(ws + 12582912);              // 12,582,912  (6 x 2048 x 512)
    u16* ww2t  = (u16*)(ws + 25165824);              // 12,582,912  (6 x 512 x 2048)
    u16* wlmt  = (u16*)(ws + 37748736);              //    131,072  (128 x 512)
    u16* xb    = (u16*)(ws + 37879808);              // 67,108,864  residual (bf16, in-place y)
    char* big  = ws + 104988672;                     // chunk*4096 bytes transient

    // Adaptive token chunking. Transient per chunk:
    //   qkv (chunk*1536*2) + attno (chunk*512*2) = chunk*4096  (attn phase)
    //   h1  (chunk*2048*2)                       = chunk*4096  (mlp phase)
    const size_t fixed_bytes = 104988672ull;
    int chunk = 4096;
    const int cands[4] = {65536, 32768, 16384, 8192};
    for (int i = 0; i < 4; i++) {
        if (fixed_bytes + (size_t)cands[i] * 4096ull <= ws_size) { chunk = cands[i]; break; }
    }
    const int nchunks = NTOK / chunk;
    u16* qkvc  = (u16*)big;                          // chunk x 1536
    u16* attnc = (u16*)(big + (size_t)chunk * 3072); // chunk x 512
    u16* h1c   = (u16*)big;                          // chunk x 2048

    // weight conversion (every call: d_ws is re-poisoned before timed launches)
    conv_qkv_k<<<6 * 1536 * 512 / 256, 256, 0, stream>>>(wq, wk, wvp, wqkvt);
    conv_t_k  <<<6 * 512 * 512 / 256, 256, 0, stream>>>(proj_w, wprjt, 512, 512);
    conv_t_k  <<<6 * 512 * 2048 / 256, 256, 0, stream>>>(w1, ww1t, 512, 2048);
    conv_t_k  <<<6 * 2048 * 512 / 256, 256, 0, stream>>>(w2, ww2t, 2048, 512);
    conv_lm_k <<<128 * 512 / 256, 256, 0, stream>>>(lm_w, wlmt);

    embed_k<<<NTOK, 256, 0, stream>>>(idx, tokt, post, xb);

    for (int l = 0; l < NLAYER; l++) {
        // ---- attention phase, chunked over tokens ----
        for (int c = 0; c < nchunks; c++) {
            const size_t t0 = (size_t)c * chunk;
            // qkv = x @ Wqkv  (no bias)
            gemm_bt<0><<<dim3(12, chunk / 128), 256, 0, stream>>>(
                xb + t0 * 512, wqkvt + (size_t)l * 786432, qkvc,
                nullptr, nullptr, 512, 1536, 1536);
            // attention (chunk-local)
            attn_k<<<chunk / 4, 256, 0, stream>>>(qkvc, attnc);
            // x = attno @ proj_w + proj_b + x   (in-place residual)
            gemm_bt<1><<<dim3(4, chunk / 128), 256, 0, stream>>>(
                attnc, wprjt + (size_t)l * 262144, xb + t0 * 512,
                proj_b + l * 512, xb + t0 * 512, 512, 512, 512);
        }
        // x = LN1(x)  (in-place)
        ln_k<<<NTOK / 4, 256, 0, stream>>>(xb, ln1_g + l * 512, ln1_b + l * 512, xb);
        // ---- MLP phase, chunked over tokens ----
        for (int c = 0; c < nchunks; c++) {
            const size_t t0 = (size_t)c * chunk;
            // h1 = relu(x @ w1 + b1)
            gemm_bt<2><<<dim3(16, chunk / 128), 256, 0, stream>>>(
                xb + t0 * 512, ww1t + (size_t)l * 1048576, h1c,
                b1 + l * 2048, nullptr, 512, 2048, 2048);
            // x = h1 @ w2 + b2 + x   (in-place residual)
            gemm_bt<1><<<dim3(4, chunk / 128), 256, 0, stream>>>(
                h1c, ww2t + (size_t)l * 1048576, xb + t0 * 512,
                b2 + l * 512, xb + t0 * 512, 2048, 512, 512);
        }
        // x = LN2(x)  (in-place)
        ln_k<<<NTOK / 4, 256, 0, stream>>>(xb, ln2_g + l * 512, ln2_b + l * 512, xb);
    }

    // logits = x @ lm_w + lm_b  (N padded to 128, masked fp32 store, Nout=65)
    gemm_bt<3><<<dim3(1, 512), 256, 0, stream>>>(
        xb, wlmt, out, lm_b, nullptr, 512, 128, VOCAB);
}

// Round 4
// 4162.871 us; speedup vs baseline: 1.2599x; 1.0381x over previous
//
#include <hip/hip_runtime.h>
#include <hip/hip_bf16.h>
#include <math.h>

// Problem constants
#define NTOK  65536      // B*T
#define CDIM  512
#define NHEAD 8
#define HSZ   64
#define NLAYER 6
#define DFF   2048
#define VOCAB 65

typedef unsigned short u16;
typedef __attribute__((ext_vector_type(8))) __bf16 bf16x8;
typedef __attribute__((ext_vector_type(4))) float f32x4;
typedef __attribute__((ext_vector_type(8))) unsigned short ushort8;

__device__ __forceinline__ float b2f(u16 u) {
    union { unsigned int i; float f; } x; x.i = ((unsigned int)u) << 16; return x.f;
}
__device__ __forceinline__ u16 f2b(float f) {
    union { float f; unsigned int i; } x; x.f = f;
    unsigned int r = x.i + 0x7fffu + ((x.i >> 16) & 1u);   // RNE
    return (u16)(r >> 16);
}

__device__ __forceinline__ void async16(const u16* g, u16* l) {
    __builtin_amdgcn_global_load_lds(
        (const __attribute__((address_space(1))) void*)g,
        (__attribute__((address_space(3))) void*)l, 16, 0, 0);
}

// ---------------------------------------------------------------------------
// GEMM: C[M x N] = A[M x K] @ Bt[N x K]^T   (A,Bt bf16; fp32 MFMA accum)
// EPI: 0 plain->bf16, 1 +bias+res->bf16 (res may alias Cout: in-place),
//      2 relu(+bias)->bf16, 3 +bias->f32 masked col<Nout
// 256x128 tile, 512 threads (8 waves, each 64x64), BK=64, LDS 48 KB
// (3 blocks/CU). 256 MFMA per barrier-pair vs 48 KB staging: 1.55x better
// MFMA:staging ratio than R3's 128x128. XCD swizzle: id%8 = XCD owns whole
// m-stripes (L2 locality for A). Requires gridDim.y % 8 == 0.
// ---------------------------------------------------------------------------
template<int EPI>
__global__ __launch_bounds__(512)
void gemm_bt(const u16* __restrict__ A, const u16* __restrict__ Bt,
             void* __restrict__ Cout, const float* __restrict__ bias,
             const u16* __restrict__ res, int K, int N, int Nout)
{
    __shared__ u16 lA[2 * 256 * 32];   // [s][row<256][32]  32 KB
    __shared__ u16 lB[2 * 128 * 32];   // [s][row<128][32]  16 KB
    const int tid  = threadIdx.x;

    // XCD-aware swizzle
    const int Nx = gridDim.x;
    const int id = blockIdx.y * Nx + blockIdx.x;
    const int xcd = id & 7;
    const int j   = id >> 3;
    const int mt  = xcd + 8 * (j / Nx);
    const int nt  = j - (j / Nx) * Nx;
    const int m0  = mt * 256;
    const int n0  = nt * 128;

    const int lane = tid & 63;
    const int wv   = tid >> 6;         // 0..7
    const int wr   = (wv >> 1) * 64;   // wave row offset in tile (0,64,128,192)
    const int wc   = (wv & 1) * 64;    // wave col offset (0,64)
    const int r16  = lane & 15;
    const int quad = lane >> 4;

    f32x4 acc[4][4] = {};

    // staging per BK=64 step: A 2048 16B-chunks (4/thread), B 1024 (2/thread).
    // chunk c -> s=k-half, row, kseg: lA[s][row][kseg*8] contiguous = c*8.
    const int srow = tid >> 2, skseg = (tid & 3) * 8;
    const u16* pA = A  + (size_t)(m0 + srow) * K + skseg;   // + row 128 below
    const u16* pB = Bt + (size_t)(n0 + srow) * K + skseg;
    const size_t r128K = (size_t)128 * K;
    u16* lA0 = &lA[(size_t)tid * 8];
    u16* lB0 = &lB[(size_t)tid * 8];

    for (int k0 = 0; k0 < K; k0 += 64) {
        async16(pA + k0,              lA0);           // s0, row srow
        async16(pA + r128K + k0,      lA0 + 4096);    // s0, row srow+128
        async16(pA + 32 + k0,         lA0 + 8192);    // s1, row srow
        async16(pA + r128K + 32 + k0, lA0 + 12288);   // s1, row srow+128
        async16(pB + k0,              lB0);           // s0, row srow
        async16(pB + 32 + k0,         lB0 + 4096);    // s1, row srow
        __syncthreads();   // drains vmcnt -> LDS valid

#pragma unroll
        for (int s = 0; s < 2; s++) {
            const u16* bA = &lA[s * 8192];
            const u16* bB = &lB[s * 4096];
            bf16x8 af[4], bfr[4];
#pragma unroll
            for (int i = 0; i < 4; i++)
                af[i] = *(const bf16x8*)(const void*)&bA[(wr + i * 16 + r16) * 32 + quad * 8];
#pragma unroll
            for (int jj = 0; jj < 4; jj++)
                bfr[jj] = *(const bf16x8*)(const void*)&bB[(wc + jj * 16 + r16) * 32 + quad * 8];
#pragma unroll
            for (int i = 0; i < 4; i++)
#pragma unroll
                for (int jj = 0; jj < 4; jj++)
                    acc[i][jj] = __builtin_amdgcn_mfma_f32_16x16x32_bf16(af[i], bfr[jj], acc[i][jj], 0, 0, 0);
        }
        __syncthreads();   // all reads done before next stage overwrites
    }

    // epilogue: C/D layout col=lane&15, row=quad*4+reg  [m89-verified]
#pragma unroll
    for (int jj = 0; jj < 4; jj++) {
        const int col = n0 + wc + jj * 16 + r16;
        float bv = 0.f;
        if (EPI == 1 || EPI == 2) bv = bias[col];
        if (EPI == 3) bv = (col < Nout) ? bias[col] : 0.f;
#pragma unroll
        for (int i = 0; i < 4; i++) {
            const int row0 = m0 + wr + i * 16 + quad * 4;
#pragma unroll
            for (int r = 0; r < 4; r++) {
                float v = acc[i][jj][r] + bv;
                const size_t rr = (size_t)(row0 + r);
                if (EPI == 1) v += b2f(res[rr * N + col]);
                if (EPI == 2) v = fmaxf(v, 0.f);
                if (EPI == 3) {
                    if (col < Nout) ((float*)Cout)[rr * (size_t)Nout + col] = v;
                } else {
                    ((u16*)Cout)[rr * N + col] = f2b(v);
                }
            }
        }
    }
}

// ---------------------------------------------------------------------------
// Attention: one wave per (b,h). T=8, HS=64. qkv layout [token][q|k|v, h*64+d].
// NOTE: reference scale = C^-0.5 = 512^-0.5 (not HS^-0.5).
// ---------------------------------------------------------------------------
__global__ __launch_bounds__(256)
void attn_k(const u16* __restrict__ qkv, u16* __restrict__ out)
{
    __shared__ float sq[4][8][64], sk[4][8][64], sv[4][8][64], sp[4][64];
    const int w = threadIdx.x >> 6, lane = threadIdx.x & 63;
    const int unit = blockIdx.x * 4 + w;        // local b*8 + h
    const int b = unit >> 3, h = unit & 7;
    const size_t base = (size_t)b * 8 * 1536 + h * 64;
#pragma unroll
    for (int t = 0; t < 8; t++) {
        sq[w][t][lane] = b2f(qkv[base + t * 1536 + lane]);
        sk[w][t][lane] = b2f(qkv[base + t * 1536 + 512 + lane]);
        sv[w][t][lane] = b2f(qkv[base + t * 1536 + 1024 + lane]);
    }
    __syncthreads();
    const int t = lane >> 3, s = lane & 7;
    float sc = -1e30f;
    if (s <= t) {
        float d = 0.f;
#pragma unroll
        for (int c = 0; c < 64; c++) d += sq[w][t][c] * sk[w][s][c];
        sc = d * 0.04419417382415922f;          // 512^-0.5
    }
    float mx = sc;
#pragma unroll
    for (int m = 1; m < 8; m <<= 1) mx = fmaxf(mx, __shfl_xor(mx, m, 8));
    float e = __expf(sc - mx);
    if (s > t) e = 0.f;
    float sum = e;
#pragma unroll
    for (int m = 1; m < 8; m <<= 1) sum += __shfl_xor(sum, m, 8);
    sp[w][lane] = e / sum;
    __syncthreads();
#pragma unroll
    for (int tt = 0; tt < 8; tt++) {
        float a = 0.f;
#pragma unroll
        for (int ss = 0; ss < 8; ss++) a += sp[w][tt * 8 + ss] * sv[w][ss][lane];
        out[((size_t)b * 8 + tt) * 512 + h * 64 + lane] = f2b(a);
    }
}

// ---------------------------------------------------------------------------
// LayerNorm: wave per token, 8 elems/lane, shuffle reduction. In-place OK.
// ---------------------------------------------------------------------------
__global__ __launch_bounds__(256)
void ln_k(const u16* __restrict__ y, const float* __restrict__ g,
          const float* __restrict__ be, u16* __restrict__ x)
{
    const int w = threadIdx.x >> 6, lane = threadIdx.x & 63;
    const size_t tok = (size_t)blockIdx.x * 4 + w;
    const u16* row = y + tok * 512 + lane * 8;
    ushort8 raw = *(const ushort8*)(const void*)row;
    float v[8];
#pragma unroll
    for (int i = 0; i < 8; i++) v[i] = b2f(raw[i]);
    float s = 0.f;
#pragma unroll
    for (int i = 0; i < 8; i++) s += v[i];
#pragma unroll
    for (int m = 1; m < 64; m <<= 1) s += __shfl_xor(s, m, 64);
    const float mu = s * (1.f / 512.f);
    float q = 0.f;
#pragma unroll
    for (int i = 0; i < 8; i++) { float d = v[i] - mu; q += d * d; }
#pragma unroll
    for (int m = 1; m < 64; m <<= 1) q += __shfl_xor(q, m, 64);
    const float inv = rsqrtf(q * (1.f / 512.f) + 1e-5f);
    f32x4 g0  = *(const f32x4*)(const void*)&g[lane * 8];
    f32x4 g1  = *(const f32x4*)(const void*)&g[lane * 8 + 4];
    f32x4 b0  = *(const f32x4*)(const void*)&be[lane * 8];
    f32x4 b1v = *(const f32x4*)(const void*)&be[lane * 8 + 4];
    ushort8 o;
#pragma unroll
    for (int i = 0; i < 4; i++) o[i]     = f2b((v[i] - mu) * inv * g0[i] + b0[i]);
#pragma unroll
    for (int i = 0; i < 4; i++) o[i + 4] = f2b((v[i + 4] - mu) * inv * g1[i] + b1v[i]);
    *(ushort8*)(void*)&x[tok * 512 + lane * 8] = o;
}

// ---------------------------------------------------------------------------
// Embedding: block per token, x = tok_table[idx] + pos_table -> bf16
// ---------------------------------------------------------------------------
__global__ __launch_bounds__(256)
void embed_k(const int* __restrict__ idx, const float* __restrict__ tokt,
             const float* __restrict__ pos, u16* __restrict__ xb)
{
    const int tk = blockIdx.x;
    const int t = tk & 7;
    const int ix = idx[tk];
    const int c = threadIdx.x;
    const size_t o = (size_t)tk * 512;
    xb[o + c]       = f2b(tokt[(size_t)ix * 512 + c]       + pos[t * 512 + c]);
    xb[o + c + 256] = f2b(tokt[(size_t)ix * 512 + c + 256] + pos[t * 512 + c + 256]);
}

// ---------------------------------------------------------------------------
// Weight converts (fp32 -> bf16 B^T layouts), once per launch
// ---------------------------------------------------------------------------
__global__ __launch_bounds__(256)
void conv_qkv_k(const float* __restrict__ wq, const float* __restrict__ wk,
                const float* __restrict__ wv, u16* __restrict__ out)
{
    int gid = blockIdx.x * 256 + threadIdx.x;        // < 6*1536*512
    int l = gid / 786432;
    int rem = gid - l * 786432;
    int j = rem >> 9, c = rem & 511;
    int sel = j >> 9;
    int jj = j & 511;
    int h = jj >> 6, d = jj & 63;
    const float* src = (sel == 0) ? wq : (sel == 1) ? wk : wv;
    out[gid] = f2b(src[(((size_t)l * 8 + h) * 512 + c) * 64 + d]);
}

// out[l][n][k] = in[l][k][n]  (per-layer K x N -> N x K transpose)
__global__ __launch_bounds__(256)
void conv_t_k(const float* __restrict__ in, u16* __restrict__ out, int K, int N)
{
    int gid = blockIdx.x * 256 + threadIdx.x;        // < 6*K*N
    int per = K * N;
    int l = gid / per;
    int rem = gid - l * per;
    int n = rem / K;
    int k = rem - n * K;
    out[gid] = f2b(in[(size_t)l * per + (size_t)k * N + n]);
}

// lm_t[128][512], rows >= 65 zero-padded
__global__ __launch_bounds__(256)
void conv_lm_k(const float* __restrict__ lm_w, u16* __restrict__ out)
{
    int gid = blockIdx.x * 256 + threadIdx.x;        // < 128*512
    int n = gid >> 9, c = gid & 511;
    out[gid] = (n < VOCAB) ? f2b(lm_w[(size_t)c * VOCAB + n]) : (u16)0;
}

// ---------------------------------------------------------------------------
extern "C" void kernel_launch(void* const* d_in, const int* in_sizes, int n_in,
                              void* d_out, int out_size, void* d_ws, size_t ws_size,
                              hipStream_t stream)
{
    const int*   idx    = (const int*)  d_in[0];
    const float* tokt   = (const float*)d_in[1];
    const float* post   = (const float*)d_in[2];
    const float* wq     = (const float*)d_in[3];
    const float* wk     = (const float*)d_in[4];
    const float* wvp    = (const float*)d_in[5];
    const float* proj_w = (const float*)d_in[6];
    const float* proj_b = (const float*)d_in[7];
    const float* w1     = (const float*)d_in[8];
    const float* b1     = (const float*)d_in[9];
    const float* w2     = (const float*)d_in[10];
    const float* b2     = (const float*)d_in[11];
    const float* ln1_g  = (const float*)d_in[12];
    const float* ln1_b  = (const float*)d_in[13];
    const float* ln2_g  = (const float*)d_in[14];
    const float* ln2_b  = (const float*)d_in[15];
    const float* lm_w   = (const float*)d_in[16];
    const float* lm_b   = (const float*)d_in[17];
    float* out = (float*)d_out;

    char* ws = (char*)d_ws;
    // Fixed workspace layout (bytes, all 256-aligned):
    u16* wqkvt = (u16*)(ws + 0);                     //  9,437,184  (6 x 1536 x 512)
    u16* wprjt = (u16*)(ws + 9437184);               //  3,145,728  (6 x 512 x 512)
    u16* ww1t  = (u16*)(ws + 12582912);              // 12,582,912  (6 x 2048 x 512)
    u16* ww2t  = (u16*)(ws + 25165824);              // 12,582,912  (6 x 512 x 2048)
    u16* wlmt  = (u16*)(ws + 37748736);              //    131,072  (128 x 512)
    u16* xb    = (u16*)(ws + 37879808);              // 67,108,864  residual (bf16, in-place y)
    char* big  = ws + 104988672;                     // chunk*4096 bytes transient

    // Adaptive token chunking. Transient per chunk:
    //   qkv (chunk*1536*2) + attno (chunk*512*2) = chunk*4096  (attn phase)
    //   h1  (chunk*2048*2)                       = chunk*4096  (mlp phase)
    const size_t fixed_bytes = 104988672ull;
    int chunk = 4096;
    const int cands[4] = {65536, 32768, 16384, 8192};
    for (int i = 0; i < 4; i++) {
        if (fixed_bytes + (size_t)cands[i] * 4096ull <= ws_size) { chunk = cands[i]; break; }
    }
    const int nchunks = NTOK / chunk;
    u16* qkvc  = (u16*)big;                          // chunk x 1536
    u16* attnc = (u16*)(big + (size_t)chunk * 3072); // chunk x 512
    u16* h1c   = (u16*)big;                          // chunk x 2048

    // weight conversion (every call: d_ws is re-poisoned before timed launches)
    conv_qkv_k<<<6 * 1536 * 512 / 256, 256, 0, stream>>>(wq, wk, wvp, wqkvt);
    conv_t_k  <<<6 * 512 * 512 / 256, 256, 0, stream>>>(proj_w, wprjt, 512, 512);
    conv_t_k  <<<6 * 512 * 2048 / 256, 256, 0, stream>>>(w1, ww1t, 512, 2048);
    conv_t_k  <<<6 * 2048 * 512 / 256, 256, 0, stream>>>(w2, ww2t, 2048, 512);
    conv_lm_k <<<128 * 512 / 256, 256, 0, stream>>>(lm_w, wlmt);

    embed_k<<<NTOK, 256, 0, stream>>>(idx, tokt, post, xb);

    for (int l = 0; l < NLAYER; l++) {
        // ---- attention phase, chunked over tokens ----
        for (int c = 0; c < nchunks; c++) {
            const size_t t0 = (size_t)c * chunk;
            // qkv = x @ Wqkv  (no bias)
            gemm_bt<0><<<dim3(12, chunk / 256), 512, 0, stream>>>(
                xb + t0 * 512, wqkvt + (size_t)l * 786432, qkvc,
                nullptr, nullptr, 512, 1536, 1536);
            // attention (chunk-local)
            attn_k<<<chunk / 4, 256, 0, stream>>>(qkvc, attnc);
            // x = attno @ proj_w + proj_b + x   (in-place residual)
            gemm_bt<1><<<dim3(4, chunk / 256), 512, 0, stream>>>(
                attnc, wprjt + (size_t)l * 262144, xb + t0 * 512,
                proj_b + l * 512, xb + t0 * 512, 512, 512, 512);
        }
        // x = LN1(x)  (in-place)
        ln_k<<<NTOK / 4, 256, 0, stream>>>(xb, ln1_g + l * 512, ln1_b + l * 512, xb);
        // ---- MLP phase, chunked over tokens ----
        for (int c = 0; c < nchunks; c++) {
            const size_t t0 = (size_t)c * chunk;
            // h1 = relu(x @ w1 + b1)
            gemm_bt<2><<<dim3(16, chunk / 256), 512, 0, stream>>>(
                xb + t0 * 512, ww1t + (size_t)l * 1048576, h1c,
                b1 + l * 2048, nullptr, 512, 2048, 2048);
            // x = h1 @ w2 + b2 + x   (in-place residual)
            gemm_bt<1><<<dim3(4, chunk / 256), 512, 0, stream>>>(
                h1c, ww2t + (size_t)l * 1048576, xb + t0 * 512,
                b2 + l * 512, xb + t0 * 512, 2048, 512, 512);
        }
        // x = LN2(x)  (in-place)
        ln_k<<<NTOK / 4, 256, 0, stream>>>(xb, ln2_g + l * 512, ln2_b + l * 512, xb);
    }

    // logits = x @ lm_w + lm_b  (N padded to 128, masked fp32 store, Nout=65)
    gemm_bt<3><<<dim3(1, 256), 512, 0, stream>>>(
        xb, wlmt, out, lm_b, nullptr, 512, 128, VOCAB);
}